// Round 1
// baseline (208.975 us; speedup 1.0000x reference)
//
#include <hip/hip_runtime.h>

#define B_DIM 64
#define C_DIM 768
#define HID_DIM 768
#define HW_DIM 24          // H == W == 24
#define PLANE 576          // 24*24
#define KCH 96             // k-chunk for FC kernels
#define OT 64              // o-tile for FC kernels

__device__ __forceinline__ float hatcdf(float t) {
    // piecewise "hat" CDF: 0 for t<=-1, 0.5(t+1)^2 for -1<t<=0,
    // 1-0.5(1-t)^2 for 0<t<=1, 1 for t>1
    float u = fminf(fmaxf(t, -1.f), 1.f);
    float a = u + 1.f;
    float b = 1.f - u;
    return (t <= 0.f) ? 0.5f * a * a : 1.f - 0.5f * b * b;
}

// K1: feat[b,c] = S_b * sum_{h,w} X[b,c,h,w] * wy[h] * wx[w]
// grid (C/4, B), block 256 (4 waves, one channel plane per wave).
// Also zeroes the x1raw/x2raw accumulators (98304 floats at zbuf).
__global__ __launch_bounds__(256) void pool_kernel(
    const float* __restrict__ X, const float* __restrict__ box,
    float* __restrict__ feat, float* __restrict__ zbuf)
{
    const int t = threadIdx.x;
    const int gb = blockIdx.y * gridDim.x + blockIdx.x;
    if (gb < 96) {  // 96 blocks * 256 threads * float4 = 98304 floats
        reinterpret_cast<float4*>(zbuf)[gb * 256 + t] = make_float4(0.f, 0.f, 0.f, 0.f);
    }

    __shared__ float wx[HW_DIM], wy[HW_DIM];
    __shared__ float sscale;
    const int b = blockIdx.y;
    if (t < 49) {
        const float x0 = box[b * 4 + 0] * 24.f;
        const float y0 = box[b * 4 + 1] * 24.f;
        const float x1 = box[b * 4 + 2] * 24.f;
        const float y1 = box[b * 4 + 3] * 24.f;
        if (t < 24) {
            wx[t] = hatcdf(x1 - (float)t) - hatcdf(x0 - (float)t);
        } else if (t < 48) {
            const int h = t - 24;
            wy[h] = hatcdf(y1 - (float)h) - hatcdf(y0 - (float)h);
        } else {
            const float bw = (x1 - x0) * 0.25f;
            const float bh = (y1 - y0) * 0.25f;
            const float area = bw * bh;
            sscale = (area > 0.f) ? 1.f / (16.f * fmaxf(area, 1e-12f)) : 0.f;
        }
    }
    __syncthreads();

    const int wave = t >> 6;
    const int lane = t & 63;
    const int c = blockIdx.x * 4 + wave;
    const float4* __restrict__ P =
        reinterpret_cast<const float4*>(X + ((size_t)b * C_DIM + c) * PLANE);

    float acc = 0.f;
    {   // plane = 144 float4; rounds: lanes 0-63, 0-63, 0-15
        int f = lane;
        float4 v = P[f];
        int h = f / 6, wb = (f - h * 6) * 4;
        acc += wy[h] * (v.x * wx[wb] + v.y * wx[wb + 1] + v.z * wx[wb + 2] + v.w * wx[wb + 3]);
        f = lane + 64;
        v = P[f];
        h = f / 6; wb = (f - h * 6) * 4;
        acc += wy[h] * (v.x * wx[wb] + v.y * wx[wb + 1] + v.z * wx[wb + 2] + v.w * wx[wb + 3]);
        if (lane < 16) {
            f = lane + 128;
            v = P[f];
            h = f / 6; wb = (f - h * 6) * 4;
            acc += wy[h] * (v.x * wx[wb] + v.y * wx[wb + 1] + v.z * wx[wb + 2] + v.w * wx[wb + 3]);
        }
    }
    #pragma unroll
    for (int off = 32; off; off >>= 1) acc += __shfl_down(acc, off);
    if (lane == 0) feat[(size_t)b * C_DIM + c] = acc * sscale;
}

// K2/K3: Out[b,o] += sum_{k in chunk} A'[b,k] * Wm[k,o]
// where A' = RELU_IN ? relu(A + bias) : A.
// grid (HID/OT=12, HID/KCH=8), block 256. 4x4 register blocking.
template <bool RELU_IN>
__global__ __launch_bounds__(256) void fc_chunk(
    const float* __restrict__ A, const float* __restrict__ bias,
    const float* __restrict__ Wm, float* __restrict__ Out)
{
    __shared__ float As[KCH][68];   // [k][b], padded stride 68
    __shared__ float Ws[KCH][68];   // [k][o], padded stride 68
    const int t = threadIdx.x;
    const int ot = blockIdx.x * OT;
    const int kc = blockIdx.y * KCH;

    // stage A (transposed): 64 rows x KCH -> 1536 float4
    for (int j = t; j < B_DIM * (KCH / 4); j += 256) {
        const int bb = j / (KCH / 4);
        const int k4 = (j % (KCH / 4)) * 4;
        float4 v = *reinterpret_cast<const float4*>(A + (size_t)bb * HID_DIM + kc + k4);
        if constexpr (RELU_IN) {
            const float4 bv = *reinterpret_cast<const float4*>(bias + kc + k4);
            v.x = fmaxf(v.x + bv.x, 0.f);
            v.y = fmaxf(v.y + bv.y, 0.f);
            v.z = fmaxf(v.z + bv.z, 0.f);
            v.w = fmaxf(v.w + bv.w, 0.f);
        }
        As[k4 + 0][bb] = v.x;
        As[k4 + 1][bb] = v.y;
        As[k4 + 2][bb] = v.z;
        As[k4 + 3][bb] = v.w;
    }
    // stage W: KCH rows x OT -> 1536 float4
    for (int j = t; j < KCH * (OT / 4); j += 256) {
        const int k = j / (OT / 4);
        const int oo = (j % (OT / 4)) * 4;
        const float4 v = *reinterpret_cast<const float4*>(Wm + (size_t)(kc + k) * HID_DIM + ot + oo);
        *reinterpret_cast<float4*>(&Ws[k][oo]) = v;
    }
    __syncthreads();

    const int b0 = (t >> 4) * 4;   // 0..60
    const int o0 = (t & 15) * 4;   // 0..60
    float acc[4][4] = {};
    #pragma unroll 4
    for (int k = 0; k < KCH; ++k) {
        const float4 a = *reinterpret_cast<const float4*>(&As[k][b0]);
        const float4 w = *reinterpret_cast<const float4*>(&Ws[k][o0]);
        acc[0][0] += a.x * w.x; acc[0][1] += a.x * w.y; acc[0][2] += a.x * w.z; acc[0][3] += a.x * w.w;
        acc[1][0] += a.y * w.x; acc[1][1] += a.y * w.y; acc[1][2] += a.y * w.z; acc[1][3] += a.y * w.w;
        acc[2][0] += a.z * w.x; acc[2][1] += a.z * w.y; acc[2][2] += a.z * w.z; acc[2][3] += a.z * w.w;
        acc[3][0] += a.w * w.x; acc[3][1] += a.w * w.y; acc[3][2] += a.w * w.z; acc[3][3] += a.w * w.w;
    }
    #pragma unroll
    for (int i = 0; i < 4; ++i)
        #pragma unroll
        for (int j = 0; j < 4; ++j)
            atomicAdd(&Out[(size_t)(b0 + i) * HID_DIM + ot + o0 + j], acc[i][j]);
}

// K4: out[b] = b3 + sum_o relu(x2raw[b,o] + b2[o]) * w3[o]
__global__ __launch_bounds__(256) void head_kernel(
    const float* __restrict__ x2raw, const float* __restrict__ b2,
    const float* __restrict__ w3, const float* __restrict__ b3,
    float* __restrict__ out)
{
    const int b = blockIdx.x;
    const int t = threadIdx.x;
    float acc = 0.f;
    for (int o = t; o < HID_DIM; o += 256)
        acc += fmaxf(x2raw[(size_t)b * HID_DIM + o] + b2[o], 0.f) * w3[o];
    #pragma unroll
    for (int off = 32; off; off >>= 1) acc += __shfl_down(acc, off);
    __shared__ float r[4];
    if ((t & 63) == 0) r[t >> 6] = acc;
    __syncthreads();
    if (t == 0) out[b] = r[0] + r[1] + r[2] + r[3] + b3[0];
}

extern "C" void kernel_launch(void* const* d_in, const int* in_sizes, int n_in,
                              void* d_out, int out_size, void* d_ws, size_t ws_size,
                              hipStream_t stream) {
    const float* X   = (const float*)d_in[0];
    const float* box = (const float*)d_in[1];
    const float* w1  = (const float*)d_in[2];
    const float* b1  = (const float*)d_in[3];
    const float* w2  = (const float*)d_in[4];
    const float* b2  = (const float*)d_in[5];
    const float* w3  = (const float*)d_in[6];
    const float* b3  = (const float*)d_in[7];
    float* out = (float*)d_out;

    float* feat  = (float*)d_ws;                 // 64*768
    float* x1raw = feat + B_DIM * HID_DIM;       // 64*768
    float* x2raw = x1raw + B_DIM * HID_DIM;      // 64*768

    // K1 zeroes x1raw..x2raw (contiguous 98304 floats) and computes feat
    pool_kernel<<<dim3(C_DIM / 4, B_DIM), 256, 0, stream>>>(X, box, feat, x1raw);
    fc_chunk<false><<<dim3(HID_DIM / OT, HID_DIM / KCH), 256, 0, stream>>>(feat, b1, w1, x1raw);
    fc_chunk<true><<<dim3(HID_DIM / OT, HID_DIM / KCH), 256, 0, stream>>>(x1raw, b1, w2, x2raw);
    head_kernel<<<B_DIM, 256, 0, stream>>>(x2raw, b2, w3, b3, out);
}